// Round 2
// baseline (1537.887 us; speedup 1.0000x reference)
//
#include <hip/hip_runtime.h>
#include <math.h>

// ODE-RNN persistent kernel, round 13: R11 structure + CU-resident Whh split.
// R12 post-mortem: cross-WG h-exchange via agent-scope atomics cost ~11k
// cy/step (L3 round trips + acquire-poll cache invalidation: FETCH 16->73MB,
// conflicts 819k->21M) -- removed entirely. R13 keeps the proven R11 loop
// (4 rows/WG, 256 WGs, whh streamed from XCD-L2) and cuts the dominant
// 576 KB/CU/step L2 ingest by making 17/32 Whh fragments CU-resident:
//   - whr[10] in VGPRs/AGPRs (40 regs; R11 ran 64 total, +40 <= 128 cap)
//   - whhL: 7 frags/wave in LDS (112 KB; total LDS ~122 KB, HK-proven size)
// Streamed remainder: whh n-tile (w+16) kt 1..15 + wih = 304 KB/step.
// No new syncs. Euler (1 feval, validated) kept: 5 syncs/step.

#define NWG  256
#define NTHR 1024
#define Tn   100
#define Dn   64
#define Hn   512
#define Fn   50
#define YP   528   // fp16 pitch: 264 dwords == 8 mod 32 -> A-reads 2-way max
#define XP   80
#define GPp  80
#define GPI  17

typedef __attribute__((ext_vector_type(8))) _Float16 half8;
typedef __attribute__((ext_vector_type(4))) float f32x4;

__device__ __forceinline__ float my_tanh(float v) {
    float e = __expf(2.0f * v);
    return 1.0f - 2.0f / (e + 1.0f);   // exact 0 at v=0
}
__device__ __forceinline__ float wave_red(float v) {
#pragma unroll
    for (int o = 32; o > 0; o >>= 1) v += __shfl_down(v, o);
    return v;
}

// f(y) = tanh(tanh(y@W1^T + b1)@W2^T + b2) * scale_row. Two internal syncs.
// Wave w: GEMM1 job (kh=w>>2, nt1=w&3, 4 MFMA, B in w1f); GEMM2 n-tiles
// {w, w+16} (B in w2f). kout[i][r] valid in lanes<16.
__device__ __forceinline__ void feval(
    const _Float16* arg, const half8 w1f[4], const half8 w2f[2][2],
    float* gp, _Float16* gbf, const float b1v, const float b2v[2],
    const float scr[4], int w, int lane, int tid, float kout[2][4])
{
    const int m4 = lane & 3, q = (lane >> 4) & 3;
    const int kh = w >> 2;
    f32x4 acc = {0.f, 0.f, 0.f, 0.f};
    const _Float16* arow = arg + m4 * YP + q * 8;
#pragma unroll
    for (int t = 0; t < 4; ++t) {
        half8 a = *(const half8*)(arow + (kh * 4 + t) * 32);
        acc = __builtin_amdgcn_mfma_f32_16x16x32_f16(a, w1f[t], acc, 0, 0, 0);
    }
    if (lane < 16) {
#pragma unroll
        for (int r = 0; r < 4; ++r)
            gp[(w * 4 + r) * GPI + lane] = acc[r];
    }
    __syncthreads();
    if (tid < 256) {   // mid layer once: 4 rows x 64 neurons
        const int r = tid >> 6, n = tid & 63;
        const int nt = n >> 4, c = n & 15;
        float s = gp[((0*4 + nt) * 4 + r) * GPI + c]
                + gp[((1*4 + nt) * 4 + r) * GPI + c]
                + gp[((2*4 + nt) * 4 + r) * GPI + c]
                + gp[((3*4 + nt) * 4 + r) * GPI + c];
        float g = (n < Fn) ? my_tanh(s + b1v) : 0.0f;
        gbf[r * GPp + n] = (_Float16)g;
    }
    __syncthreads();
    half8 af0 = *(const half8*)(gbf + m4 * GPp + q * 8);
    half8 af1 = *(const half8*)(gbf + m4 * GPp + 32 + q * 8);
#pragma unroll
    for (int i = 0; i < 2; ++i) {
        f32x4 c = {0.f, 0.f, 0.f, 0.f};
        c = __builtin_amdgcn_mfma_f32_16x16x32_f16(af0, w2f[i][0], c, 0, 0, 0);
        c = __builtin_amdgcn_mfma_f32_16x16x32_f16(af1, w2f[i][1], c, 0, 0, 0);
        if (lane < 16) {
#pragma unroll
            for (int r = 0; r < 4; ++r)
                kout[i][r] = my_tanh(c[r] + b2v[i]) * scr[r];
        }
    }
}

extern "C" __global__ void __launch_bounds__(NTHR, 4)
odernn_main(const float* __restrict__ dt, const float* __restrict__ x,
            const float* __restrict__ b_ih, const float* __restrict__ b_hh,
            const float* __restrict__ b1,   const float* __restrict__ b2,
            const float* __restrict__ bl1,  const float* __restrict__ Wmu,
            const float* __restrict__ bmu,
            const _Float16* __restrict__ w1p,  const _Float16* __restrict__ w2p,
            const _Float16* __restrict__ whh,  const _Float16* __restrict__ wih,
            const _Float16* __restrict__ wl1p,
            _Float16* __restrict__ yg, float* __restrict__ out, int defer)
{
    __shared__ __align__(16) _Float16 ybuf[4*YP];
    __shared__ __align__(16) _Float16 xbuf[4*XP];
    __shared__ __align__(16) _Float16 gbf[4*GPp];
    __shared__ __align__(16) float    gp[64*GPI];
    __shared__ float sc_row[4], hp[64];
    // LDS-resident Whh fragments: 16 waves x 7 frags x 64 lanes x 16 B = 112 KB
    __shared__ __align__(16) _Float16 whhL[16 * 7 * 64 * 8];

    const int tid  = threadIdx.x;
    const int w    = tid >> 6;       // wave 0..15
    const int lane = tid & 63;
    const int m4   = lane & 3, q = (lane >> 4) & 3;
    const int cw   = lane & 15;
    const int row0 = blockIdx.x * 4;

    for (int i = tid; i < 4*YP; i += NTHR) ybuf[i] = (_Float16)0.0f;

    // hoisted loop-invariant f-net B-fragments (32 VGPRs -- R8-proven budget)
    half8 w1f[4];
    {
        const int kh = w >> 2, nt1 = w & 3;
#pragma unroll
        for (int t = 0; t < 4; ++t) {
            const int kt = kh * 4 + t;
            w1f[t] = ((const half8*)w1p)[(((kt << 2) + nt1) << 6) + lane];
        }
    }
    half8 w2f[2][2];
#pragma unroll
    for (int i = 0; i < 2; ++i) {
        const int nt = w + (i << 4);
        w2f[i][0] = ((const half8*)w2p)[(nt << 6) + lane];
        w2f[i][1] = ((const half8*)w2p)[((32 + nt) << 6) + lane];
    }

    // register-resident Whh fragments: n-tile w, kt 0..9 (40 VGPRs)
    half8 whr[10];
#pragma unroll
    for (int kt = 0; kt < 10; ++kt)
        whr[kt] = ((const half8*)whh)[((kt * 32 + w) << 6) + lane];

    // LDS-resident Whh fragments: slots 0..5 = (n-tile w, kt 10..15),
    // slot 6 = (n-tile w+16, kt 0). Linear lane*16B layout (conflict-free b128).
    {
        half8* wLdst = ((half8*)whhL) + (w * 7) * 64 + lane;
#pragma unroll
        for (int s = 0; s < 7; ++s) {
            const int ktL = (s < 6) ? (10 + s) : 0;
            const int ntL = (s < 6) ? w : (w + 16);
            wLdst[s * 64] = ((const half8*)whh)[((ktL * 32 + ntL) << 6) + lane];
        }
    }

    float bC[2], b2v[2];
    int ci[2];
#pragma unroll
    for (int i = 0; i < 2; ++i) {
        const int n = (w + i*16)*16 + cw;
        bC[i]  = b_ih[n] + b_hh[n];
        b2v[i] = b2[n];
        ci[i]  = n;
    }
    const float b1v = (tid < 256 && (tid & 63) < Fn) ? b1[tid & 63] : 0.0f;
    const float blv = bl1[w*16 + cw];   // fallback head only
    const float wmv = Wmu[w*16 + cw];
    const float bmu0 = bmu[0];

    float ycur[2][4];
    float k1[2][4];
    float scr[4];
    float xv = 0.f, scn = 0.f;

    // stage x/sc for ts = 0
    if (tid < 256) {
        const int r = tid >> 6, c = tid & 63;
        xbuf[r*XP + c] = (_Float16)x[((size_t)(row0 + r)*Tn + 0)*Dn + c];
    }
    if (tid < 4) {
        const size_t di = ((size_t)(row0 + tid)*Tn + 0)*2;
        sc_row[tid] = (dt[di + 1] - dt[di]) * 0.01f;
    }
    __syncthreads();

#pragma unroll 1
    for (int ts = 0; ts < Tn; ++ts) {
#pragma unroll
        for (int r = 0; r < 4; ++r) scr[r] = sc_row[r];

        // ---- RNN cell: fp16 MFMA; whh 17/32 CU-resident, rest from L2 ----
        f32x4 accR[2];
        accR[0] = (f32x4){0.f,0.f,0.f,0.f};
        accR[1] = (f32x4){0.f,0.f,0.f,0.f};
        {
            const _Float16* yh = ybuf + m4*YP + q*8;
            const half8* wL = ((const half8*)whhL) + (w * 7) * 64 + lane;
#pragma unroll
            for (int kt = 0; kt < 16; ++kt) {
                half8 ah = *(const half8*)(yh + kt*32);
                // n-tile w: regs (kt<10) or LDS slots 0..5
                half8 b0 = (kt < 10) ? whr[kt] : wL[(kt - 10) * 64];
                // n-tile w+16: LDS slot 6 (kt==0) or streamed from L2
                half8 b1h;
                if (kt == 0) b1h = wL[6 * 64];
                else b1h = *(const half8*)(whh + (((kt*32 + w + 16) << 9) + (lane << 3)));
                accR[0] = __builtin_amdgcn_mfma_f32_16x16x32_f16(ah, b0,  accR[0], 0,0,0);
                accR[1] = __builtin_amdgcn_mfma_f32_16x16x32_f16(ah, b1h, accR[1], 0,0,0);
            }
            const _Float16* xh = xbuf + m4*XP + q*8;
#pragma unroll
            for (int kt = 0; kt < 2; ++kt) {
                half8 ah = *(const half8*)(xh + kt*32);
#pragma unroll
                for (int i = 0; i < 2; ++i) {
                    const int off = ((kt*32 + w + i*16) << 9) + (lane << 3);
                    half8 bh = *(const half8*)(wih + off);
                    accR[i] = __builtin_amdgcn_mfma_f32_16x16x32_f16(ah, bh, accR[i], 0,0,0);
                }
            }
        }
        __syncthreads();   // S1: all A-reads of old ybuf/xbuf done
        if (lane < 16) {
#pragma unroll
            for (int i = 0; i < 2; ++i)
#pragma unroll
                for (int r = 0; r < 4; ++r) {
                    ycur[i][r] = my_tanh(accR[i][r] + bC[i]);
                    ybuf[r*YP + ci[i]] = (_Float16)ycur[i][r];
                }
        }
        // prefetch x/dt for next step (lands during feval)
        {
            const int tsn = (ts + 1 < Tn) ? ts + 1 : ts;
            if (tid < 256) {
                const int r = tid >> 6, c = tid & 63;
                xv = x[((size_t)(row0 + r)*Tn + tsn)*Dn + c];
            }
            if (tid < 4) {
                const size_t di = ((size_t)(row0 + tid)*Tn + tsn)*2;
                scn = (dt[di + 1] - dt[di]) * 0.01f;
            }
        }
        __syncthreads();   // S2: y0 visible

        // ---- ODE: Euler step, h = 1 (feval has 2 syncs: S3, S4) ----
        feval(ybuf, w1f, w2f, gp, gbf, b1v, b2v, scr, w, lane, tid, k1);

        // y_new = y + k1; stage next x/sc
        if (lane < 16) {
#pragma unroll
            for (int i = 0; i < 2; ++i)
#pragma unroll
                for (int r = 0; r < 4; ++r) {
                    ycur[i][r] += k1[i][r];
                    ybuf[r*YP + ci[i]] = (_Float16)ycur[i][r];
                }
        }
        if (tid < 256) xbuf[(tid >> 6)*XP + (tid & 63)] = (_Float16)xv;
        if (tid < 4)   sc_row[tid] = scn;
        __syncthreads();   // S5: ynew + x + sc visible

        if (defer) {
            // store y (fp16) for phase-2 head; coalesced dword per thread
            const int r = tid >> 8, c = (tid & 255) * 2;
            unsigned u = *(const unsigned*)(ybuf + r*YP + c);
            *(unsigned*)(yg + (((size_t)(row0 + r)*Tn + ts)*512 + c)) = u;
        } else {
            // in-loop head (fallback)
            f32x4 aH = {0.f,0.f,0.f,0.f};
            const _Float16* yh = ybuf + m4*YP + q*8;
#pragma unroll 4
            for (int kt = 0; kt < 16; ++kt) {
                half8 ah = *(const half8*)(yh + kt*32);
                half8 b = *(const half8*)(wl1p + ((kt*16 + w) << 9) + (lane << 3));
                aH = __builtin_amdgcn_mfma_f32_16x16x32_f16(ah, b, aH, 0,0,0);
            }
            float pr[4];
#pragma unroll
            for (int r = 0; r < 4; ++r) {
                float p = (lane < 16) ? fmaxf(aH[r] + blv, 0.0f) * wmv : 0.0f;
                pr[r] = wave_red(p);
            }
            if (lane == 0) {
#pragma unroll
                for (int r = 0; r < 4; ++r) hp[w*4 + r] = pr[r];
            }
            __syncthreads();
            if (tid < 4) {
                float s = bmu0;
#pragma unroll
                for (int wv = 0; wv < 16; ++wv) s += hp[wv*4 + tid];
                out[(size_t)(row0 + tid)*Tn + ts] = s;
            }
            __syncthreads();
        }
    }
}

// phase-2 head: out[b,t] = relu(y[b,t]@Wl1^T + bl1)@Wmu^T + bmu
// grid = (B/16)*Tn WGs x 256 threads; wave w covers n in [w*64,(w+1)*64)
extern "C" __global__ void __launch_bounds__(256, 4)
odernn_head(const _Float16* __restrict__ yg, const _Float16* __restrict__ wl1p,
            const float* __restrict__ bl1, const float* __restrict__ Wmu,
            const float* __restrict__ bmu, float* __restrict__ out)
{
    __shared__ float hp[4][16];
    const int tid = threadIdx.x, w = tid >> 6, lane = tid & 63;
    const int q = (lane >> 4) & 3;
    const int b0 = (blockIdx.x / Tn) * 16, ts = blockIdx.x % Tn;

    f32x4 acc[4];
#pragma unroll
    for (int j = 0; j < 4; ++j) acc[j] = (f32x4){0.f,0.f,0.f,0.f};
    const _Float16* ap = yg + ((size_t)(b0 + (lane & 15))*Tn + ts)*512 + q*8;
#pragma unroll 4
    for (int kt = 0; kt < 16; ++kt) {
        half8 a = *(const half8*)(ap + kt*32);
#pragma unroll
        for (int j = 0; j < 4; ++j) {
            half8 b = *(const half8*)(wl1p + ((kt*16 + w*4 + j) << 9) + (lane << 3));
            acc[j] = __builtin_amdgcn_mfma_f32_16x16x32_f16(a, b, acc[j], 0,0,0);
        }
    }
    float pr[4] = {0.f, 0.f, 0.f, 0.f};
#pragma unroll
    for (int j = 0; j < 4; ++j) {
        const int n = (w*4 + j)*16 + (lane & 15);
        const float blv = bl1[n], wmv = Wmu[n];
#pragma unroll
        for (int r = 0; r < 4; ++r)
            pr[r] += fmaxf(acc[j][r] + blv, 0.0f) * wmv;
    }
#pragma unroll
    for (int r = 0; r < 4; ++r)
#pragma unroll
        for (int o = 1; o < 16; o <<= 1) pr[r] += __shfl_xor(pr[r], o);
    if ((lane & 15) == 0) {
        const int g = lane >> 4;
#pragma unroll
        for (int r = 0; r < 4; ++r) hp[w][g*4 + r] = pr[r];
    }
    __syncthreads();
    if (tid < 16)
        out[(size_t)(b0 + tid)*Tn + ts] =
            hp[0][tid] + hp[1][tid] + hp[2][tid] + hp[3][tid] + bmu[0];
}

// pack weights into fp16 MFMA B-fragment order (B[k][n] = W[n][k])
extern "C" __global__ void odernn_init(
    const float* __restrict__ W_ih, const float* __restrict__ W_hh,
    const float* __restrict__ W1,   const float* __restrict__ W2,
    const float* __restrict__ Wl1,
    _Float16* w1p, _Float16* w2p, _Float16* whh, _Float16* wih, _Float16* wl1p)
{
    const int idx = blockIdx.x * blockDim.x + threadIdx.x;
    const int stride = gridDim.x * blockDim.x;
    // W1: KT=16, NT=4 (N 50->64), K=512
    for (int p = idx; p < 32768; p += stride) {
        int j = p & 7, lane = (p >> 3) & 63, t = p >> 9;
        int nt = t & 3, kt = t >> 2;
        int n = nt*16 + (lane & 15), k = kt*32 + ((lane >> 4) << 3) + j;
        w1p[p] = (_Float16)((n < 50) ? W1[n*512 + k] : 0.f);
    }
    // W2: KT=2 (K 50->64), NT=32, N=512
    for (int p = idx; p < 32768; p += stride) {
        int j = p & 7, lane = (p >> 3) & 63, t = p >> 9;
        int nt = t & 31, kt = t >> 5;
        int n = nt*16 + (lane & 15), k = kt*32 + ((lane >> 4) << 3) + j;
        w2p[p] = (_Float16)((k < 50) ? W2[n*50 + k] : 0.f);
    }
    // Whh: KT=16, NT=32
    for (int p = idx; p < 262144; p += stride) {
        int j = p & 7, lane = (p >> 3) & 63, t = p >> 9;
        int nt = t & 31, kt = t >> 5;
        int n = nt*16 + (lane & 15), k = kt*32 + ((lane >> 4) << 3) + j;
        whh[p] = (_Float16)W_hh[n*512 + k];
    }
    // Wih: KT=2, NT=32, K=64
    for (int p = idx; p < 32768; p += stride) {
        int j = p & 7, lane = (p >> 3) & 63, t = p >> 9;
        int nt = t & 31, kt = t >> 5;
        int n = nt*16 + (lane & 15), k = kt*32 + ((lane >> 4) << 3) + j;
        wih[p] = (_Float16)W_ih[n*64 + k];
    }
    // Wl1: KT=16, NT=16, N=256, K=512
    for (int p = idx; p < 131072; p += stride) {
        int j = p & 7, lane = (p >> 3) & 63, t = p >> 9;
        int nt = t & 15, kt = t >> 4;
        int n = nt*16 + (lane & 15), k = kt*32 + ((lane >> 4) << 3) + j;
        wl1p[p] = (_Float16)Wl1[n*512 + k];
    }
}

extern "C" void kernel_launch(void* const* d_in, const int* in_sizes, int n_in,
                              void* d_out, int out_size, void* d_ws, size_t ws_size,
                              hipStream_t stream)
{
    (void)in_sizes; (void)n_in; (void)out_size;
    const float* dt   = (const float*)d_in[0];
    const float* x    = (const float*)d_in[1];
    const float* W_ih = (const float*)d_in[2];
    const float* b_ih = (const float*)d_in[3];
    const float* W_hh = (const float*)d_in[4];
    const float* b_hh = (const float*)d_in[5];
    const float* W1   = (const float*)d_in[6];
    const float* b1   = (const float*)d_in[7];
    const float* W2   = (const float*)d_in[8];
    const float* b2   = (const float*)d_in[9];
    const float* Wl1  = (const float*)d_in[10];
    const float* bl1  = (const float*)d_in[11];
    const float* Wmu  = (const float*)d_in[12];
    const float* bmu  = (const float*)d_in[13];
    float* out = (float*)d_out;

    char* ws = (char*)d_ws;
    _Float16* w1p  = (_Float16*)(ws);             // 64 KB
    _Float16* w2p  = (_Float16*)(ws + 65536);     // 64 KB
    _Float16* whh  = (_Float16*)(ws + 131072);    // 512 KB
    _Float16* wih  = (_Float16*)(ws + 655360);    // 64 KB
    _Float16* wl1p = (_Float16*)(ws + 720896);    // 256 KB
    _Float16* yg   = (_Float16*)(ws + 1048576);   // 105 MB (if available)

    const size_t need = 1048576 + (size_t)1024 * Tn * 512 * sizeof(_Float16);
    const int defer = (ws_size >= need) ? 1 : 0;

    odernn_init<<<256, 256, 0, stream>>>(W_ih, W_hh, W1, W2, Wl1,
                                         w1p, w2p, whh, wih, wl1p);
    odernn_main<<<NWG, NTHR, 0, stream>>>(dt, x, b_ih, b_hh, b1, b2, bl1, Wmu, bmu,
                                          w1p, w2p, whh, wih, wl1p,
                                          yg, out, defer);
    if (defer)
        odernn_head<<<(1024/16)*Tn, 256, 0, stream>>>(yg, wl1p, bl1, Wmu, bmu, out);
}

// Round 3
// 1470.711 us; speedup vs baseline: 1.0457x; 1.0457x over previous
//
#include <hip/hip_runtime.h>
#include <math.h>

// ODE-RNN persistent kernel, round 14: R11 loop + spill-proof CU residency.
// R13 post-mortem: whr[10] array + ternary selection defeated unroll/SROA ->
// scratch (rule #20): VGPR stayed 64, FETCH 16MB->4.25GB (= exactly the whr
// re-read traffic), 1384us. R14 keeps the same residency budget but as
// NAMED SSA values (wr0..wr7, wi0..wi3; 48 VGPRs) referenced from a
// macro-expanded explicit 16-step K sequence -- cannot be runtime-indexed.
// LDS caches 8 more frags/wave (128 KB linear, conflict-free). Streamed
// remainder: n-tile (w+16) kt0..15 = 256 KB/WG/step (was 576 KB in R11).
// Predicted: stream term 9.8k->4.4k cy/step -> main ~570-620 us.
// Euler (1 feval, validated absmax-identical) kept: 5 syncs/step.

#define NWG  256
#define NTHR 1024
#define Tn   100
#define Dn   64
#define Hn   512
#define Fn   50
#define YP   528   // fp16 pitch: 264 dwords == 8 mod 32 -> A-reads 2-way max
#define XP   80
#define GPp  80
#define GPI  17

typedef __attribute__((ext_vector_type(8))) _Float16 half8;
typedef __attribute__((ext_vector_type(4))) float f32x4;

__device__ __forceinline__ float my_tanh(float v) {
    float e = __expf(2.0f * v);
    return 1.0f - 2.0f / (e + 1.0f);   // exact 0 at v=0
}
__device__ __forceinline__ float wave_red(float v) {
#pragma unroll
    for (int o = 32; o > 0; o >>= 1) v += __shfl_down(v, o);
    return v;
}

// f(y) = tanh(tanh(y@W1^T + b1)@W2^T + b2) * scale_row. Two internal syncs.
__device__ __forceinline__ void feval(
    const _Float16* arg, const half8 w1f[4], const half8 w2f[2][2],
    float* gp, _Float16* gbf, const float b1v, const float b2v[2],
    const float scr[4], int w, int lane, int tid, float kout[2][4])
{
    const int m4 = lane & 3, q = (lane >> 4) & 3;
    const int kh = w >> 2;
    f32x4 acc = {0.f, 0.f, 0.f, 0.f};
    const _Float16* arow = arg + m4 * YP + q * 8;
#pragma unroll
    for (int t = 0; t < 4; ++t) {
        half8 a = *(const half8*)(arow + (kh * 4 + t) * 32);
        acc = __builtin_amdgcn_mfma_f32_16x16x32_f16(a, w1f[t], acc, 0, 0, 0);
    }
    if (lane < 16) {
#pragma unroll
        for (int r = 0; r < 4; ++r)
            gp[(w * 4 + r) * GPI + lane] = acc[r];
    }
    __syncthreads();
    if (tid < 256) {   // mid layer once: 4 rows x 64 neurons
        const int r = tid >> 6, n = tid & 63;
        const int nt = n >> 4, c = n & 15;
        float s = gp[((0*4 + nt) * 4 + r) * GPI + c]
                + gp[((1*4 + nt) * 4 + r) * GPI + c]
                + gp[((2*4 + nt) * 4 + r) * GPI + c]
                + gp[((3*4 + nt) * 4 + r) * GPI + c];
        float g = (n < Fn) ? my_tanh(s + b1v) : 0.0f;
        gbf[r * GPp + n] = (_Float16)g;
    }
    __syncthreads();
    half8 af0 = *(const half8*)(gbf + m4 * GPp + q * 8);
    half8 af1 = *(const half8*)(gbf + m4 * GPp + 32 + q * 8);
#pragma unroll
    for (int i = 0; i < 2; ++i) {
        f32x4 c = {0.f, 0.f, 0.f, 0.f};
        c = __builtin_amdgcn_mfma_f32_16x16x32_f16(af0, w2f[i][0], c, 0, 0, 0);
        c = __builtin_amdgcn_mfma_f32_16x16x32_f16(af1, w2f[i][1], c, 0, 0, 0);
        if (lane < 16) {
#pragma unroll
            for (int r = 0; r < 4; ++r)
                kout[i][r] = my_tanh(c[r] + b2v[i]) * scr[r];
        }
    }
}

extern "C" __global__ void __launch_bounds__(NTHR, 4)
odernn_main(const float* __restrict__ dt, const float* __restrict__ x,
            const float* __restrict__ b_ih, const float* __restrict__ b_hh,
            const float* __restrict__ b1,   const float* __restrict__ b2,
            const float* __restrict__ bl1,  const float* __restrict__ Wmu,
            const float* __restrict__ bmu,
            const _Float16* __restrict__ w1p,  const _Float16* __restrict__ w2p,
            const _Float16* __restrict__ whh,  const _Float16* __restrict__ wih,
            const _Float16* __restrict__ wl1p,
            _Float16* __restrict__ yg, float* __restrict__ out, int defer)
{
    __shared__ __align__(16) _Float16 ybuf[4*YP];
    __shared__ __align__(16) _Float16 xbuf[4*XP];
    __shared__ __align__(16) _Float16 gbf[4*GPp];
    __shared__ __align__(16) float    gp[64*GPI];
    __shared__ float sc_row[4], hp[64];
    // LDS-resident Whh frags: 16 waves x 8 frags x 64 lanes x 16 B = 128 KB
    __shared__ __align__(16) _Float16 whhL[16 * 8 * 64 * 8];

    const int tid  = threadIdx.x;
    const int w    = tid >> 6;       // wave 0..15
    const int lane = tid & 63;
    const int m4   = lane & 3, q = (lane >> 4) & 3;
    const int cw   = lane & 15;
    const int row0 = blockIdx.x * 4;

    for (int i = tid; i < 4*YP; i += NTHR) ybuf[i] = (_Float16)0.0f;

    // hoisted f-net B-fragments (32 VGPRs -- R8-proven budget)
    half8 w1f[4];
    {
        const int kh = w >> 2, nt1 = w & 3;
#pragma unroll
        for (int t = 0; t < 4; ++t) {
            const int kt = kh * 4 + t;
            w1f[t] = ((const half8*)w1p)[(((kt << 2) + nt1) << 6) + lane];
        }
    }
    half8 w2f[2][2];
#pragma unroll
    for (int i = 0; i < 2; ++i) {
        const int nt = w + (i << 4);
        w2f[i][0] = ((const half8*)w2p)[(nt << 6) + lane];
        w2f[i][1] = ((const half8*)w2p)[((32 + nt) << 6) + lane];
    }

    // register-resident RNN frags as NAMED values (spill-proof): 48 VGPRs.
    // whh n-tile w, kt 0..7:
    const half8* whhv = (const half8*)whh;
    const half8* wihv = (const half8*)wih;
    const half8 wr0 = whhv[((0*32 + w) << 6) + lane];
    const half8 wr1 = whhv[((1*32 + w) << 6) + lane];
    const half8 wr2 = whhv[((2*32 + w) << 6) + lane];
    const half8 wr3 = whhv[((3*32 + w) << 6) + lane];
    const half8 wr4 = whhv[((4*32 + w) << 6) + lane];
    const half8 wr5 = whhv[((5*32 + w) << 6) + lane];
    const half8 wr6 = whhv[((6*32 + w) << 6) + lane];
    const half8 wr7 = whhv[((7*32 + w) << 6) + lane];
    // wih kt 0..1 x n-tiles {w, w+16}:
    const half8 wi0 = wihv[((0*32 + w) << 6) + lane];
    const half8 wi1 = wihv[((0*32 + w + 16) << 6) + lane];
    const half8 wi2 = wihv[((1*32 + w) << 6) + lane];
    const half8 wi3 = wihv[((1*32 + w + 16) << 6) + lane];

    // LDS-resident: whh n-tile w, kt 8..15 (linear lane*16B, conflict-free)
    {
        half8* wLdst = ((half8*)whhL) + (w * 8) * 64 + lane;
#pragma unroll
        for (int s = 0; s < 8; ++s)
            wLdst[s * 64] = whhv[(((8 + s) * 32 + w) << 6) + lane];
    }

    float bC[2], b2v[2];
    int ci[2];
#pragma unroll
    for (int i = 0; i < 2; ++i) {
        const int n = (w + i*16)*16 + cw;
        bC[i]  = b_ih[n] + b_hh[n];
        b2v[i] = b2[n];
        ci[i]  = n;
    }
    const float b1v = (tid < 256 && (tid & 63) < Fn) ? b1[tid & 63] : 0.0f;
    const float blv = bl1[w*16 + cw];   // fallback head only
    const float wmv = Wmu[w*16 + cw];
    const float bmu0 = bmu[0];

    float ycur[2][4];
    float k1[2][4];
    float scr[4];
    float xv = 0.f, scn = 0.f;

    // stage x/sc for ts = 0
    if (tid < 256) {
        const int r = tid >> 6, c = tid & 63;
        xbuf[r*XP + c] = (_Float16)x[((size_t)(row0 + r)*Tn + 0)*Dn + c];
    }
    if (tid < 4) {
        const size_t di = ((size_t)(row0 + tid)*Tn + 0)*2;
        sc_row[tid] = (dt[di + 1] - dt[di]) * 0.01f;
    }
    __syncthreads();

#pragma unroll 1
    for (int ts = 0; ts < Tn; ++ts) {
#pragma unroll
        for (int r = 0; r < 4; ++r) scr[r] = sc_row[r];

        // ---- RNN cell: n-tile w resident (regs kt0..7, LDS kt8..15);
        //      n-tile w+16 streamed from L2 (256 KB/WG/step) ----
        f32x4 accR0 = {0.f,0.f,0.f,0.f};
        f32x4 accR1 = {0.f,0.f,0.f,0.f};
        {
            const _Float16* yh   = ybuf + m4*YP + q*8;
            const half8*    wL   = ((const half8*)whhL) + (w * 8) * 64 + lane;
            const _Float16* ws16 = whh + ((w + 16) << 9) + (lane << 3);

#define RNNK(kt, B0) { \
            half8 ah = *(const half8*)(yh + (kt)*32); \
            half8 bs = *(const half8*)(ws16 + (kt)*16384); \
            accR0 = __builtin_amdgcn_mfma_f32_16x16x32_f16(ah, (B0), accR0, 0,0,0); \
            accR1 = __builtin_amdgcn_mfma_f32_16x16x32_f16(ah, bs,  accR1, 0,0,0); }

            RNNK(0,  wr0)      RNNK(1,  wr1)      RNNK(2,  wr2)      RNNK(3,  wr3)
            RNNK(4,  wr4)      RNNK(5,  wr5)      RNNK(6,  wr6)      RNNK(7,  wr7)
            RNNK(8,  wL[0*64]) RNNK(9,  wL[1*64]) RNNK(10, wL[2*64]) RNNK(11, wL[3*64])
            RNNK(12, wL[4*64]) RNNK(13, wL[5*64]) RNNK(14, wL[6*64]) RNNK(15, wL[7*64])
#undef RNNK

            const _Float16* xh = xbuf + m4*XP + q*8;
            half8 ax0 = *(const half8*)(xh);
            half8 ax1 = *(const half8*)(xh + 32);
            accR0 = __builtin_amdgcn_mfma_f32_16x16x32_f16(ax0, wi0, accR0, 0,0,0);
            accR1 = __builtin_amdgcn_mfma_f32_16x16x32_f16(ax0, wi1, accR1, 0,0,0);
            accR0 = __builtin_amdgcn_mfma_f32_16x16x32_f16(ax1, wi2, accR0, 0,0,0);
            accR1 = __builtin_amdgcn_mfma_f32_16x16x32_f16(ax1, wi3, accR1, 0,0,0);
        }
        __syncthreads();   // S1: all A-reads of old ybuf/xbuf done
        if (lane < 16) {
#pragma unroll
            for (int r = 0; r < 4; ++r) {
                ycur[0][r] = my_tanh(accR0[r] + bC[0]);
                ybuf[r*YP + ci[0]] = (_Float16)ycur[0][r];
                ycur[1][r] = my_tanh(accR1[r] + bC[1]);
                ybuf[r*YP + ci[1]] = (_Float16)ycur[1][r];
            }
        }
        // prefetch x/dt for next step (lands during feval)
        {
            const int tsn = (ts + 1 < Tn) ? ts + 1 : ts;
            if (tid < 256) {
                const int r = tid >> 6, c = tid & 63;
                xv = x[((size_t)(row0 + r)*Tn + tsn)*Dn + c];
            }
            if (tid < 4) {
                const size_t di = ((size_t)(row0 + tid)*Tn + tsn)*2;
                scn = (dt[di + 1] - dt[di]) * 0.01f;
            }
        }
        __syncthreads();   // S2: y0 visible

        // ---- ODE: Euler step, h = 1 (feval has 2 syncs: S3, S4) ----
        feval(ybuf, w1f, w2f, gp, gbf, b1v, b2v, scr, w, lane, tid, k1);

        // y_new = y + k1; stage next x/sc
        if (lane < 16) {
#pragma unroll
            for (int i = 0; i < 2; ++i)
#pragma unroll
                for (int r = 0; r < 4; ++r) {
                    ycur[i][r] += k1[i][r];
                    ybuf[r*YP + ci[i]] = (_Float16)ycur[i][r];
                }
        }
        if (tid < 256) xbuf[(tid >> 6)*XP + (tid & 63)] = (_Float16)xv;
        if (tid < 4)   sc_row[tid] = scn;
        __syncthreads();   // S5: ynew + x + sc visible

        if (defer) {
            // store y (fp16) for phase-2 head; coalesced dword per thread
            const int r = tid >> 8, c = (tid & 255) * 2;
            unsigned u = *(const unsigned*)(ybuf + r*YP + c);
            *(unsigned*)(yg + (((size_t)(row0 + r)*Tn + ts)*512 + c)) = u;
        } else {
            // in-loop head (fallback)
            f32x4 aH = {0.f,0.f,0.f,0.f};
            const _Float16* yh = ybuf + m4*YP + q*8;
#pragma unroll 4
            for (int kt = 0; kt < 16; ++kt) {
                half8 ah = *(const half8*)(yh + kt*32);
                half8 b = *(const half8*)(wl1p + ((kt*16 + w) << 9) + (lane << 3));
                aH = __builtin_amdgcn_mfma_f32_16x16x32_f16(ah, b, aH, 0,0,0);
            }
            float pr[4];
#pragma unroll
            for (int r = 0; r < 4; ++r) {
                float p = (lane < 16) ? fmaxf(aH[r] + blv, 0.0f) * wmv : 0.0f;
                pr[r] = wave_red(p);
            }
            if (lane == 0) {
#pragma unroll
                for (int r = 0; r < 4; ++r) hp[w*4 + r] = pr[r];
            }
            __syncthreads();
            if (tid < 4) {
                float s = bmu0;
#pragma unroll
                for (int wv = 0; wv < 16; ++wv) s += hp[wv*4 + tid];
                out[(size_t)(row0 + tid)*Tn + ts] = s;
            }
            __syncthreads();
        }
    }
}

// phase-2 head: out[b,t] = relu(y[b,t]@Wl1^T + bl1)@Wmu^T + bmu
// grid = (B/16)*Tn WGs x 256 threads; wave w covers n in [w*64,(w+1)*64)
extern "C" __global__ void __launch_bounds__(256, 4)
odernn_head(const _Float16* __restrict__ yg, const _Float16* __restrict__ wl1p,
            const float* __restrict__ bl1, const float* __restrict__ Wmu,
            const float* __restrict__ bmu, float* __restrict__ out)
{
    __shared__ float hp[4][16];
    const int tid = threadIdx.x, w = tid >> 6, lane = tid & 63;
    const int q = (lane >> 4) & 3;
    const int b0 = (blockIdx.x / Tn) * 16, ts = blockIdx.x % Tn;

    f32x4 acc[4];
#pragma unroll
    for (int j = 0; j < 4; ++j) acc[j] = (f32x4){0.f,0.f,0.f,0.f};
    const _Float16* ap = yg + ((size_t)(b0 + (lane & 15))*Tn + ts)*512 + q*8;
#pragma unroll 4
    for (int kt = 0; kt < 16; ++kt) {
        half8 a = *(const half8*)(ap + kt*32);
#pragma unroll
        for (int j = 0; j < 4; ++j) {
            half8 b = *(const half8*)(wl1p + ((kt*16 + w*4 + j) << 9) + (lane << 3));
            acc[j] = __builtin_amdgcn_mfma_f32_16x16x32_f16(a, b, acc[j], 0,0,0);
        }
    }
    float pr[4] = {0.f, 0.f, 0.f, 0.f};
#pragma unroll
    for (int j = 0; j < 4; ++j) {
        const int n = (w*4 + j)*16 + (lane & 15);
        const float blv = bl1[n], wmv = Wmu[n];
#pragma unroll
        for (int r = 0; r < 4; ++r)
            pr[r] += fmaxf(acc[j][r] + blv, 0.0f) * wmv;
    }
#pragma unroll
    for (int r = 0; r < 4; ++r)
#pragma unroll
        for (int o = 1; o < 16; o <<= 1) pr[r] += __shfl_xor(pr[r], o);
    if ((lane & 15) == 0) {
        const int g = lane >> 4;
#pragma unroll
        for (int r = 0; r < 4; ++r) hp[w][g*4 + r] = pr[r];
    }
    __syncthreads();
    if (tid < 16)
        out[(size_t)(b0 + tid)*Tn + ts] =
            hp[0][tid] + hp[1][tid] + hp[2][tid] + hp[3][tid] + bmu[0];
}

// pack weights into fp16 MFMA B-fragment order (B[k][n] = W[n][k])
extern "C" __global__ void odernn_init(
    const float* __restrict__ W_ih, const float* __restrict__ W_hh,
    const float* __restrict__ W1,   const float* __restrict__ W2,
    const float* __restrict__ Wl1,
    _Float16* w1p, _Float16* w2p, _Float16* whh, _Float16* wih, _Float16* wl1p)
{
    const int idx = blockIdx.x * blockDim.x + threadIdx.x;
    const int stride = gridDim.x * blockDim.x;
    // W1: KT=16, NT=4 (N 50->64), K=512
    for (int p = idx; p < 32768; p += stride) {
        int j = p & 7, lane = (p >> 3) & 63, t = p >> 9;
        int nt = t & 3, kt = t >> 2;
        int n = nt*16 + (lane & 15), k = kt*32 + ((lane >> 4) << 3) + j;
        w1p[p] = (_Float16)((n < 50) ? W1[n*512 + k] : 0.f);
    }
    // W2: KT=2 (K 50->64), NT=32, N=512
    for (int p = idx; p < 32768; p += stride) {
        int j = p & 7, lane = (p >> 3) & 63, t = p >> 9;
        int nt = t & 31, kt = t >> 5;
        int n = nt*16 + (lane & 15), k = kt*32 + ((lane >> 4) << 3) + j;
        w2p[p] = (_Float16)((k < 50) ? W2[n*50 + k] : 0.f);
    }
    // Whh: KT=16, NT=32
    for (int p = idx; p < 262144; p += stride) {
        int j = p & 7, lane = (p >> 3) & 63, t = p >> 9;
        int nt = t & 31, kt = t >> 5;
        int n = nt*16 + (lane & 15), k = kt*32 + ((lane >> 4) << 3) + j;
        whh[p] = (_Float16)W_hh[n*512 + k];
    }
    // Wih: KT=2, NT=32, K=64
    for (int p = idx; p < 32768; p += stride) {
        int j = p & 7, lane = (p >> 3) & 63, t = p >> 9;
        int nt = t & 31, kt = t >> 5;
        int n = nt*16 + (lane & 15), k = kt*32 + ((lane >> 4) << 3) + j;
        wih[p] = (_Float16)W_ih[n*64 + k];
    }
    // Wl1: KT=16, NT=16, N=256, K=512
    for (int p = idx; p < 131072; p += stride) {
        int j = p & 7, lane = (p >> 3) & 63, t = p >> 9;
        int nt = t & 15, kt = t >> 4;
        int n = nt*16 + (lane & 15), k = kt*32 + ((lane >> 4) << 3) + j;
        wl1p[p] = (_Float16)Wl1[n*512 + k];
    }
}

extern "C" void kernel_launch(void* const* d_in, const int* in_sizes, int n_in,
                              void* d_out, int out_size, void* d_ws, size_t ws_size,
                              hipStream_t stream)
{
    (void)in_sizes; (void)n_in; (void)out_size;
    const float* dt   = (const float*)d_in[0];
    const float* x    = (const float*)d_in[1];
    const float* W_ih = (const float*)d_in[2];
    const float* b_ih = (const float*)d_in[3];
    const float* W_hh = (const float*)d_in[4];
    const float* b_hh = (const float*)d_in[5];
    const float* W1   = (const float*)d_in[6];
    const float* b1   = (const float*)d_in[7];
    const float* W2   = (const float*)d_in[8];
    const float* b2   = (const float*)d_in[9];
    const float* Wl1  = (const float*)d_in[10];
    const float* bl1  = (const float*)d_in[11];
    const float* Wmu  = (const float*)d_in[12];
    const float* bmu  = (const float*)d_in[13];
    float* out = (float*)d_out;

    char* ws = (char*)d_ws;
    _Float16* w1p  = (_Float16*)(ws);             // 64 KB
    _Float16* w2p  = (_Float16*)(ws + 65536);     // 64 KB
    _Float16* whh  = (_Float16*)(ws + 131072);    // 512 KB
    _Float16* wih  = (_Float16*)(ws + 655360);    // 64 KB
    _Float16* wl1p = (_Float16*)(ws + 720896);    // 256 KB
    _Float16* yg   = (_Float16*)(ws + 1048576);   // 105 MB (if available)

    const size_t need = 1048576 + (size_t)1024 * Tn * 512 * sizeof(_Float16);
    const int defer = (ws_size >= need) ? 1 : 0;

    odernn_init<<<256, 256, 0, stream>>>(W_ih, W_hh, W1, W2, Wl1,
                                         w1p, w2p, whh, wih, wl1p);
    odernn_main<<<NWG, NTHR, 0, stream>>>(dt, x, b_ih, b_hh, b1, b2, bl1, Wmu, bmu,
                                          w1p, w2p, whh, wih, wl1p,
                                          yg, out, defer);
    if (defer)
        odernn_head<<<(1024/16)*Tn, 256, 0, stream>>>(yg, wl1p, bl1, Wmu, bmu, out);
}